// Round 20
// baseline (99.654 us; speedup 1.0000x reference)
//
#include <hip/hip_runtime.h>
#include <math.h>

#define S      4096
#define BEV    16
#define KNN    5
#define BIGF   1.0e9f
#define NSL    32           // slices per candidate scan
#define GPP    8            // query-QUADS per knn block -> 32 rows/block
#define NTH    256          // = GPP * NSL
#define RSTR4  161          // per-slice LDS row stride in elements (GPP*20 + 1 pad)

__device__ __forceinline__ float fmulrn(float a, float b) { return __fmul_rn(a, b); }
__device__ __forceinline__ float faddrn(float a, float b) { return __fadd_rn(a, b); }

// ---- K1: per-(event,chunk) stats: chunk max score, query/cand counts (no atomics) ----
__global__ __launch_bounds__(1024) void k_scan(const float* __restrict__ score,
                                               float* __restrict__ mrss4,
                                               int* __restrict__ qn, int* __restrict__ cn) {
    int blk = blockIdx.x, t = threadIdx.x;
    int b = blk >> 2, ch = blk & 3;
    float v = score[(size_t)b * S + ch * 1024 + t];
    float m = v;
    int pk = (v > 0.5f) ? (1 << 16) : 1;
#pragma unroll
    for (int off = 32; off >= 1; off >>= 1) {
        m = fmaxf(m, __shfl_xor(m, off, 64));
        pk += __shfl_xor(pk, off, 64);
    }
    __shared__ float wm[16];
    __shared__ int wp[16];
    int wid = t >> 6;
    if ((t & 63) == 0) { wm[wid] = m; wp[wid] = pk; }
    __syncthreads();
    if (t == 0) {
        float mm = wm[0]; int pp = wp[0];
        for (int w = 1; w < 16; w++) { mm = fmaxf(mm, wm[w]); pp += wp[w]; }
        mrss4[blk] = mm;
        qn[blk] = pp & 0xffff;
        cn[blk] = pp >> 16;
    }
}

// ---- K2: threshold + prefix offsets; qpoff counts query QUADS ----
__global__ void k_off(const float* __restrict__ mrss4,
                      const int* __restrict__ qn, const int* __restrict__ cn,
                      float* __restrict__ thrv,
                      int* __restrict__ qchoff, int* __restrict__ cchoff,
                      int* __restrict__ qcount, int* __restrict__ ccount,
                      int* __restrict__ qpoff) {
    if (threadIdx.x != 0) return;
    float mn = 3.0e38f;
    for (int b = 0; b < BEV; b++) {
        float mx = mrss4[b * 4];
        for (int ch = 1; ch < 4; ch++) mx = fmaxf(mx, mrss4[b * 4 + ch]);
        mn = fminf(mn, mx);
    }
    // rn(0.98*x) monotone => min of products == product of min; clamp 0.5
    thrv[0] = fminf(__fmul_rn(mn, 0.98f), 0.5f);
    int qp = 0;
    for (int b = 0; b < BEV; b++) {
        int qq = 0, cc = 0;
        for (int ch = 0; ch < 4; ch++) {
            qchoff[b * 4 + ch] = qq; cchoff[b * 4 + ch] = cc;
            qq += qn[b * 4 + ch];    cc += cn[b * 4 + ch];
        }
        qcount[b] = qq; ccount[b] = cc;
        qpoff[b] = qp; qp += (qq + 3) >> 2;      // quads of query rows
    }
    qpoff[BEV] = qp;
}

// ---- K3: ordered compaction + sel_mask + candidate defaults + sel counts ----
__global__ __launch_bounds__(1024) void k_sel(const float* __restrict__ score,
                                              const float* __restrict__ coords,
                                              const float* __restrict__ thrv,
                                              const int* __restrict__ qchoff,
                                              const int* __restrict__ cchoff,
                                              int* __restrict__ scount,
                                              int* __restrict__ qlist,
                                              int* __restrict__ clist,
                                              float4* __restrict__ qpts,
                                              float4* __restrict__ ptsc,
                                              float* __restrict__ out_nidx,
                                              float* __restrict__ out_dist,
                                              float* __restrict__ out_w,
                                              float* __restrict__ out_sel) {
    int blk = blockIdx.x, t = threadIdx.x;
    int b = blk >> 2, ch = blk & 3;
    int p = ch * 1024 + t;
    size_t gi = (size_t)b * S + p;
    float v = score[gi];
    float thr = thrv[0];
    out_sel[gi] = (v >= thr) ? 1.0f : 0.0f;
    bool cand = (v > 0.5f);
    int pk = cand ? (1 << 16) : 1;
    int incl = pk;
#pragma unroll
    for (int off = 1; off < 64; off <<= 1) {
        int u = __shfl_up(incl, off, 64);
        if ((t & 63) >= off) incl += u;
    }
    __shared__ int wtot[16];
    __shared__ int wsel[16];
    int wid = t >> 6;
    if ((t & 63) == 63) wtot[wid] = incl;
    int sel = (v >= thr) ? 1 : 0;
#pragma unroll
    for (int off = 32; off >= 1; off >>= 1) sel += __shfl_xor(sel, off, 64);
    if ((t & 63) == 0) wsel[wid] = sel;
    __syncthreads();
    int base = 0;
    for (int w = 0; w < wid; w++) base += wtot[w];
    int excl = base + incl - pk;
    if (t == 0) {
        int sc2 = 0;
        for (int w = 0; w < 16; w++) sc2 += wsel[w];
        scount[blk] = sc2;
    }
    const float* c = coords + gi * 3;
    float x = c[0], y = c[1], z = c[2];
    float xx = faddrn(faddrn(fmulrn(x, x), fmulrn(y, y)), fmulrn(z, z));
    size_t ebase = (size_t)b * S;
    if (cand) {
        int pos = cchoff[blk] + (excl >> 16);
        clist[ebase + pos] = p;
        ptsc[ebase + pos] = make_float4(fmulrn(-2.0f, x), fmulrn(-2.0f, y),
                                        fmulrn(-2.0f, z), xx);
        // direction-0 rows: fixed default outputs
#pragma unroll
        for (int k = 0; k < KNN; k++) {
            out_nidx[gi * KNN + k] = -1.0f;
            out_dist[gi * KNN + k] = 0.0f;
            out_w[gi * KNN + k]    = 0.2f;
        }
    } else {
        int pos = qchoff[blk] + (excl & 0xffff);
        qlist[ebase + pos] = p;
        qpts[ebase + pos] = make_float4(x, y, z, xx);
    }
}

// sorted insert: compares on OLD values drive idx selects; med3 updates values.
// strict < == exact (d, pos) lexicographic order (ascending-pos scan)
#define INSM(R0,R1,R2,R3,R4,J0,J1,J2,J3,J4,dd,j) { \
    bool c0=dd<R0,c1=dd<R1,c2=dd<R2,c3=dd<R3,c4=dd<R4; \
    J4=c4?(c3?J3:j):J4; J3=c3?(c2?J2:j):J3; J2=c2?(c1?J1:j):J2; \
    J1=c1?(c0?J0:j):J1; J0=c0?j:J0; \
    R4=__builtin_amdgcn_fmed3f(dd,R3,R4); R3=__builtin_amdgcn_fmed3f(dd,R2,R3); \
    R2=__builtin_amdgcn_fmed3f(dd,R1,R2); R1=__builtin_amdgcn_fmed3f(dd,R0,R1); \
    R0=fminf(R0,dd); }

// ---- K4: fused KNN: 4 rows/thread x 32 slices, med3 insert, LDS merge + epilogue ----
__global__ __launch_bounds__(NTH, 4) void k_knn(const float4* __restrict__ ptsc,
                                                const float4* __restrict__ qpts,
                                                const int* __restrict__ qlist,
                                                const int* __restrict__ clist,
                                                const int* __restrict__ qpoff,
                                                const int* __restrict__ qcount,
                                                const int* __restrict__ ccount,
                                                const int* __restrict__ scount,
                                                float* __restrict__ out_nidx,
                                                float* __restrict__ out_dist,
                                                float* __restrict__ out_w,
                                                float* __restrict__ out_rsup) {
    int pg = blockIdx.x, t = threadIdx.x;
    if (pg == 0 && t == 0) {                     // rs_up prefix (17 floats)
        int acc = 0;
        out_rsup[0] = 0.0f;
        for (int e = 0; e < BEV; e++) {
            acc += scount[e * 4] + scount[e * 4 + 1] + scount[e * 4 + 2] + scount[e * 4 + 3];
            out_rsup[e + 1] = (float)acc;
        }
    }
    int total = qpoff[BEV];
    if (pg * GPP >= total) return;               // uniform exit

    __shared__ int sqp[BEV + 1];
    __shared__ int sqc[BEV];
    __shared__ int scc[BEV];
    __shared__ float dpart[NSL * RSTR4];         // [sl][qd*20], 20608 B
    __shared__ unsigned short ipart[NSL * RSTR4];// 10304 B
    if (t < BEV + 1) sqp[t] = qpoff[t];
    if (t < BEV) { sqc[t] = qcount[t]; scc[t] = ccount[t]; }
    __syncthreads();

    int pr = t & (GPP - 1), sl = t >> 3;         // 8 quads x 32 slices
    int gpr = pg * GPP + pr;
    bool pact = gpr < total;
    int gp = pact ? gpr : (total - 1);
    int b = 0;
#pragma unroll
    for (int e = 1; e < BEV; e++) b += (gp >= sqp[e]) ? 1 : 0;
    int rp = gp - sqp[b];
    int qc = sqc[b], cc = scc[b];
    int r0 = 4 * rp;
    size_t ebase = (size_t)b * S;
    float4 q0 = qpts[ebase + min(r0,     qc - 1)];
    float4 q1 = qpts[ebase + min(r0 + 1, qc - 1)];
    float4 q2 = qpts[ebase + min(r0 + 2, qc - 1)];
    float4 q3 = qpts[ebase + min(r0 + 3, qc - 1)];

    int slen = (cc + NSL - 1) / NSL;
    int j0 = sl * slen;
    int j1 = min(j0 + slen, cc);

    const float INF = __int_as_float(0x7f800000);
    float A0=INF,A1=INF,A2=INF,A3=INF,A4=INF; int IA0=-1,IA1=-1,IA2=-1,IA3=-1,IA4=-1;
    float B0=INF,B1=INF,B2=INF,B3=INF,B4=INF; int IB0=-1,IB1=-1,IB2=-1,IB3=-1,IB4=-1;
    float C0=INF,C1=INF,C2=INF,C3=INF,C4=INF; int IC0=-1,IC1=-1,IC2=-1,IC3=-1,IC4=-1;
    float D0=INF,D1=INF,D2=INF,D3=INF,D4=INF; int ID0=-1,ID1=-1,ID2=-1,ID3=-1,ID4=-1;
    const float4* __restrict__ pp = ptsc + ebase;

#pragma unroll 2
    for (int j = j0; j < j1; j++) {
        float4 p = pp[j];                        // 8 distinct addrs per wave
        float dm0 = faddrn(faddrn(fmulrn(p.x, q0.x), fmulrn(p.y, q0.y)), fmulrn(p.z, q0.z));
        float dd0 = fmaxf(faddrn(faddrn(q0.w, p.w), dm0), 0.0f);
        float dm1 = faddrn(faddrn(fmulrn(p.x, q1.x), fmulrn(p.y, q1.y)), fmulrn(p.z, q1.z));
        float dd1 = fmaxf(faddrn(faddrn(q1.w, p.w), dm1), 0.0f);
        float dm2 = faddrn(faddrn(fmulrn(p.x, q2.x), fmulrn(p.y, q2.y)), fmulrn(p.z, q2.z));
        float dd2 = fmaxf(faddrn(faddrn(q2.w, p.w), dm2), 0.0f);
        float dm3 = faddrn(faddrn(fmulrn(p.x, q3.x), fmulrn(p.y, q3.y)), fmulrn(p.z, q3.z));
        float dd3 = fmaxf(faddrn(faddrn(q3.w, p.w), dm3), 0.0f);
        INSM(A0,A1,A2,A3,A4, IA0,IA1,IA2,IA3,IA4, dd0, j)
        INSM(B0,B1,B2,B3,B4, IB0,IB1,IB2,IB3,IB4, dd1, j)
        INSM(C0,C1,C2,C3,C4, IC0,IC1,IC2,IC3,IC4, dd2, j)
        INSM(D0,D1,D2,D3,D4, ID0,ID1,ID2,ID3,ID4, dd3, j)
    }

    float* wd = &dpart[sl * RSTR4 + pr * 20];
    unsigned short* wi = &ipart[sl * RSTR4 + pr * 20];
    wd[0]=A0; wd[1]=A1; wd[2]=A2; wd[3]=A3; wd[4]=A4;
    wd[5]=B0; wd[6]=B1; wd[7]=B2; wd[8]=B3; wd[9]=B4;
    wd[10]=C0; wd[11]=C1; wd[12]=C2; wd[13]=C3; wd[14]=C4;
    wd[15]=D0; wd[16]=D1; wd[17]=D2; wd[18]=D3; wd[19]=D4;
    wi[0]=(unsigned short)(IA0-j0); wi[1]=(unsigned short)(IA1-j0);
    wi[2]=(unsigned short)(IA2-j0); wi[3]=(unsigned short)(IA3-j0);
    wi[4]=(unsigned short)(IA4-j0);
    wi[5]=(unsigned short)(IB0-j0); wi[6]=(unsigned short)(IB1-j0);
    wi[7]=(unsigned short)(IB2-j0); wi[8]=(unsigned short)(IB3-j0);
    wi[9]=(unsigned short)(IB4-j0);
    wi[10]=(unsigned short)(IC0-j0); wi[11]=(unsigned short)(IC1-j0);
    wi[12]=(unsigned short)(IC2-j0); wi[13]=(unsigned short)(IC3-j0);
    wi[14]=(unsigned short)(IC4-j0);
    wi[15]=(unsigned short)(ID0-j0); wi[16]=(unsigned short)(ID1-j0);
    wi[17]=(unsigned short)(ID2-j0); wi[18]=(unsigned short)(ID3-j0);
    wi[19]=(unsigned short)(ID4-j0);
    __syncthreads();

    if (t < 4 * GPP) {                           // 32 merge threads
        int pr2 = t >> 2, rs = t & 3;
        int gpr2 = pg * GPP + pr2;
        bool pact2 = gpr2 < total;
        int gp2 = pact2 ? gpr2 : (total - 1);
        int b2 = 0;
#pragma unroll
        for (int e = 1; e < BEV; e++) b2 += (gp2 >= sqp[e]) ? 1 : 0;
        int rp2 = gp2 - sqp[b2];
        int qc2 = sqc[b2], cc2 = scc[b2];
        int slen2 = (cc2 + NSL - 1) / NSL;
        int r = 4 * rp2 + rs;
        bool valid = pact2 && (r < qc2);

        unsigned long long a0=~0ull, a1u=~0ull, a2u=~0ull, a3u=~0ull, a4u=~0ull;
        for (int s2 = 0; s2 < NSL; s2++) {
            const float* dp = &dpart[s2 * RSTR4 + pr2 * 20 + rs * 5];
            const unsigned short* ip = &ipart[s2 * RSTR4 + pr2 * 20 + rs * 5];
#pragma unroll
            for (int k = 0; k < KNN; k++) {
                float d = dp[k];
                unsigned int jj = (unsigned int)(s2 * slen2 + (int)ip[k]);
                unsigned long long key = ((unsigned long long)__float_as_uint(d) << 32) | jj;
                if (key < a4u) {                  // exact (d, pos) lex order
                    a4u = key;
                    if (a4u < a3u) { unsigned long long u = a3u; a3u = a4u; a4u = u; }
                    if (a3u < a2u) { unsigned long long u = a2u; a2u = a3u; a3u = u; }
                    if (a2u < a1u) { unsigned long long u = a1u; a1u = a2u; a2u = u; }
                    if (a1u < a0)  { unsigned long long u = a0;  a0  = a1u; a1u = u; }
                }
            }
        }
        if (valid) {
            size_t eb2 = (size_t)b2 * S;
            int irow = qlist[eb2 + r];
            size_t gi = eb2 + irow;
            unsigned long long av[KNN] = {a0, a1u, a2u, a3u, a4u};
            float dk[KNN], nk[KNN], ev[KNN];
            float m = -3.0e38f;
#pragma unroll
            for (int k = 0; k < KNN; k++) {
                float d = __uint_as_float((unsigned int)(av[k] >> 32));
                bool val = (d < BIGF);
                int cpos = (int)(unsigned int)(av[k] & 0xffffffffu);
                if (!val || cpos >= S || cpos < 0) cpos = 0;
                dk[k] = val ? d : 0.0f;
                nk[k] = val ? (float)(b2 * S + clist[eb2 + cpos]) : -1.0f;
                ev[k] = expf(-dk[k]);
                m = fmaxf(m, ev[k]);
            }
            float u[KNN], ssum = 0.0f;
#pragma unroll
            for (int k = 0; k < KNN; k++) { u[k] = expf(ev[k] - m); ssum += u[k]; }
#pragma unroll
            for (int k = 0; k < KNN; k++) {
                out_nidx[gi * KNN + k] = nk[k];
                out_dist[gi * KNN + k] = dk[k];
                out_w[gi * KNN + k]    = u[k] / ssum;
            }
        }
    }
}

extern "C" void kernel_launch(void* const* d_in, const int* in_sizes, int n_in,
                              void* d_out, int out_size, void* d_ws, size_t ws_size,
                              hipStream_t stream) {
    const float* score  = (const float*)d_in[0];
    const float* coords = (const float*)d_in[1];

    float* out = (float*)d_out;
    size_t NK = (size_t)BEV * S * KNN;
    float* out_nidx = out;
    float* out_dist = out + NK;
    float* out_w    = out + 2 * NK;
    float* out_rsup = out + 3 * NK;
    float* out_sel  = out + 3 * NK + (BEV + 1);

    char* ws = (char*)d_ws;
    float* mrss4  = (float*)(ws + 0);                     // 64 f32
    int* qn       = (int*)(ws + 256);                     // 64
    int* cn       = (int*)(ws + 512);                     // 64
    int* qchoff   = (int*)(ws + 768);                     // 64
    int* cchoff   = (int*)(ws + 1024);                    // 64
    int* qcount   = (int*)(ws + 1280);                    // 16
    int* ccount   = (int*)(ws + 1344);                    // 16
    int* qpoff    = (int*)(ws + 1408);                    // 17
    int* scount   = (int*)(ws + 1536);                    // 64
    float* thrv   = (float*)(ws + 1792);                  // 1
    int* qlist    = (int*)(ws + 2048);                    // BEV*S
    int* clist    = (int*)(ws + 2048 + (size_t)BEV * S * 4);
    float4* qpts  = (float4*)(ws + 2048 + (size_t)BEV * S * 8);      // 16B aligned
    float4* ptsc  = (float4*)(ws + 2048 + (size_t)BEV * S * 8 + (size_t)BEV * S * 16);

    k_scan<<<BEV * 4, 1024, 0, stream>>>(score, mrss4, qn, cn);
    k_off<<<1, 64, 0, stream>>>(mrss4, qn, cn, thrv, qchoff, cchoff,
                                qcount, ccount, qpoff);
    k_sel<<<BEV * 4, 1024, 0, stream>>>(score, coords, thrv, qchoff, cchoff, scount,
                                        qlist, clist, qpts, ptsc,
                                        out_nidx, out_dist, out_w, out_sel);
    k_knn<<<(BEV * ((S + 3) / 4) + GPP - 1) / GPP, NTH, 0, stream>>>(
        ptsc, qpts, qlist, clist, qpoff, qcount, ccount, scount,
        out_nidx, out_dist, out_w, out_rsup);
}